// Round 10
// baseline (201.444 us; speedup 1.0000x reference)
//
#include <hip/hip_runtime.h>
#include <math.h>
#include <stddef.h>

#define NN    4096
#define BATCH 2
#define CD    64
#define KSEL  24
#define RAD2  0.2025f     // 0.45^2
#define NBINS 256
#define KBASE 1888        // (118<<4): log bins, d2 in [2^-9, 2^7) via float bits>>19
#define LCAP  255         // fits uint8 index (+1 encoding)
#define CCAP  64
#define NCP   4           // histogram copies

typedef float f4v __attribute__((ext_vector_type(4)));

__device__ __forceinline__ int d2key(unsigned bits) {
  int k = (int)(bits >> 19) - KBASE;
  return k < 0 ? 0 : (k > NBINS - 1 ? NBINS - 1 : k);
}

// per-wave redundant: scan NCP-copy 256-bin histogram; bin with cum>=KSEL (or -1) + count below
__device__ __forceinline__ int wave_bin24(const int (*h)[NBINS], int lane, int* cb_out) {
  int4 a = ((const int4*)h[0])[lane];
  int4 b = ((const int4*)h[1])[lane];
  int4 c = ((const int4*)h[2])[lane];
  int4 d = ((const int4*)h[3])[lane];
  int tt[4] = {a.x + b.x + c.x + d.x, a.y + b.y + c.y + d.y,
               a.z + b.z + c.z + d.z, a.w + b.w + c.w + d.w};
  int s = tt[0] + tt[1] + tt[2] + tt[3];
  int inc = s;
#pragma unroll
  for (int off = 1; off < 64; off <<= 1) {
    int t = __shfl_up(inc, off);
    if (lane >= off) inc += t;
  }
  int below = inc - s;
  int Bl = -1, Bb = 0;
#pragma unroll
  for (int q = 0; q < 4; ++q) {
    if (Bl < 0 && below < KSEL && below + tt[q] >= KSEL) { Bl = 4 * lane + q; Bb = below; }
    below += tt[q];
  }
  unsigned long long mk = __ballot(Bl >= 0);
  if (!mk) return -1;
  int sl = __ffsll((long long)mk) - 1;
  *cb_out = __shfl(Bb, sl);
  return __shfl(Bl, sl);
}

// ---- prep: transpose td & sd to (B,N,C); addj = clamp(log tgt_match,-20) - 0.1*tu ----
__global__ __launch_bounds__(256)
void prep_all(const float* __restrict__ td, const float* __restrict__ sd,
              const float* __restrict__ tml, const float* __restrict__ tu,
              float* __restrict__ tdT, float* __restrict__ sdT,
              float* __restrict__ addj) {
  __shared__ float tile[64][65];
  int blk = blockIdx.x;
  if (blk < 256) {
    const float* src = (blk < 128) ? td  : sd;
    float*       dst = (blk < 128) ? tdT : sdT;
    int lb = blk & 127;
    int b  = lb >> 6;
    int j0 = (lb & 63) << 6;
    int jl = threadIdx.x & 63;
    int cq = threadIdx.x >> 6;
    const float* srcp = src + (size_t)b * CD * NN;
#pragma unroll
    for (int r = 0; r < 16; ++r) {
      int c = r * 4 + cq;
      tile[c][jl] = srcp[(size_t)c * NN + j0 + jl];
    }
    __syncthreads();
    float* dstp = dst + (size_t)b * NN * CD;
#pragma unroll
    for (int r = 0; r < 16; ++r) {
      int j = r * 4 + cq;
      dstp[(size_t)(j0 + j) * CD + jl] = tile[jl][j];
    }
  } else {
    int idx = (blk - 256) * 256 + threadIdx.x;
    if (idx < BATCH * NN) {
      int b = idx >> 12, j = idx & (NN - 1);
      float l0 = tml[(size_t)b * 2 * NN + j];
      float l1 = tml[(size_t)b * 2 * NN + NN + j];
      float x  = l1 - l0;
      float sp = fmaxf(x, 0.0f) + log1pf(expf(-fabsf(x)));
      addj[idx] = fmaxf(-sp, -20.0f) - 0.1f * tu[idx];
    }
  }
}

// ---- main: 512 threads, 2 rows/block; shared tc loads; waves 0-3 row0, 4-7 row1 ----
__global__ __launch_bounds__(512, 8)
void matcher_main(const float* __restrict__ sc, const float* __restrict__ tc,
                  const float* __restrict__ sd, const float* __restrict__ td,
                  const float* __restrict__ tdT, const float* __restrict__ sdT,
                  const float* __restrict__ addj,
                  const float* __restrict__ tml, const float* __restrict__ tu,
                  const float* __restrict__ sml,
                  float* __restrict__ oexp, float* __restrict__ odisp,
                  float* __restrict__ oprob, float* __restrict__ oconf,
                  float* __restrict__ oent, float* __restrict__ osrc) {
  __shared__ __align__(16) unsigned idxb[2][NN / 4];    // 8 KB
  __shared__ __align__(16) int      hist[2][NCP][NBINS];// 8 KB
  __shared__ __align__(16) float4   sdp4[2][CD / 4];    // 512 B
  __shared__ int2     lst[2][LCAP];                     // ~4 KB (j, d2bits)
  __shared__ int2     slist[2][256];                    // 4 KB (j, score bits)
  __shared__ unsigned cand[2][CCAP];                    // 512 B
  __shared__ int      lcount[2], candn[2];

  const int tid  = threadIdx.x;
  const int w    = tid >> 6;
  const int lane = tid & 63;
  const int rg   = tid >> 8;           // row this thread serves in phases 4-7
  const int row0 = blockIdx.x * 2;
  const int b    = row0 >> 12;
  const int i0   = row0 & (NN - 1);
  const unsigned RADB = __float_as_uint(RAD2);

  // ---- init (512 int4 = exactly hist; 512 int4 = exactly idxb) ----
  ((int4*)hist)[tid] = make_int4(0, 0, 0, 0);
  ((int4*)idxb)[tid] = make_int4(0, 0, 0, 0);
  if (tid < 2) { lcount[tid] = 0; candn[tid] = 0; }
  if (sdT) {
    if (tid < 32) {
      int r = tid >> 4, t = tid & 15;
      sdp4[r][t] = ((const float4*)(sdT + ((size_t)b * NN + i0 + r) * CD))[t];
    }
  } else if (tid < 128) {
    int r = tid >> 6, c = tid & 63;
    ((float*)sdp4[r])[c] = sd[(size_t)b * CD * NN + (size_t)c * NN + i0 + r];
  }
  const float* scb = sc + (size_t)b * 3 * NN;
  const float sA0 = scb[i0],     sA1 = scb[NN + i0],     sA2 = scb[2 * NN + i0];
  const float sB0 = scb[i0 + 1], sB1 = scb[NN + i0 + 1], sB2 = scb[2 * NN + i0 + 1];
  const float4* tcx = (const float4*)(tc + (size_t)b * 3 * NN);
  const float4* tcy = tcx + NN / 4;
  const float4* tcz = tcy + NN / 4;
  const int cp = w & (NCP - 1);
  __syncthreads();                                      // barrier 1

  // ---- phase 1: each coord load feeds BOTH rows' d2; histogram only d2 < 2.0 ----
  unsigned dA[8], dB[8];
#pragma unroll
  for (int k = 0; k < 2; ++k) {
    int g = (k << 9) + tid;                             // float4-group in [0,1024)
    float4 X = tcx[g], Y = tcy[g], Z = tcz[g];
    float xs[4] = {X.x, X.y, X.z, X.w};
    float ys[4] = {Y.x, Y.y, Y.z, Y.w};
    float zs[4] = {Z.x, Z.y, Z.z, Z.w};
#pragma unroll
    for (int r = 0; r < 4; ++r) {
      float dx = xs[r] - sA0, dy = ys[r] - sA1, dz = zs[r] - sA2;
      float d2 = fmaxf(__fmaf_rn(dx, dx, __fmaf_rn(dy, dy, dz * dz)), 1e-12f);
      unsigned bits = __float_as_uint(d2);
      dA[(k << 2) + r] = bits;
      if (d2 < 2.0f) atomicAdd(&hist[0][cp][d2key(bits)], 1);
      dx = xs[r] - sB0; dy = ys[r] - sB1; dz = zs[r] - sB2;
      d2 = fmaxf(__fmaf_rn(dx, dx, __fmaf_rn(dy, dy, dz * dz)), 1e-12f);
      bits = __float_as_uint(d2);
      dB[(k << 2) + r] = bits;
      if (d2 < 2.0f) atomicAdd(&hist[1][cp][d2key(bits)], 1);
    }
  }
  __syncthreads();                                      // barrier 2

  // ---- phase 2: every wave scans both rows (needed for its compaction) ----
  int cbA = 0, cbB = 0;
  int BsA = wave_bin24(hist[0], lane, &cbA);
  int BsB = wave_bin24(hist[1], lane, &cbB);
  if (BsA < 0 || BsB < 0) {                             // block-uniform, ~1% rows
    __syncthreads();
    if (BsA < 0) {
#pragma unroll
      for (int m = 0; m < 8; ++m)
        if (__uint_as_float(dA[m]) >= 2.0f) atomicAdd(&hist[0][cp][d2key(dA[m])], 1);
    }
    if (BsB < 0) {
#pragma unroll
      for (int m = 0; m < 8; ++m)
        if (__uint_as_float(dB[m]) >= 2.0f) atomicAdd(&hist[1][cp][d2key(dB[m])], 1);
    }
    __syncthreads();
    if (BsA < 0) BsA = wave_bin24(hist[0], lane, &cbA);
    if (BsB < 0) BsB = wave_bin24(hist[1], lane, &cbB);
  }

  // ---- phase 3: compact both rows; boundary-bin bits into cand ----
#pragma unroll
  for (int m = 0; m < 8; ++m) {
    int j = ((m >> 2) << 11) + (tid << 2) + (m & 3);    // j = 4*((k<<9)+tid)+r
    unsigned bits = dA[m];
    int key = d2key(bits);
    if (key <= BsA || bits <= RADB) {
      int idx = atomicAdd(&lcount[0], 1);
      if (idx < LCAP) {
        ((unsigned char*)idxb[0])[j] = (unsigned char)(idx + 1);
        lst[0][idx] = make_int2(j, (int)bits);
      }
      if (key == BsA) { int cc = atomicAdd(&candn[0], 1); if (cc < CCAP) cand[0][cc] = bits; }
    }
    bits = dB[m];
    key = d2key(bits);
    if (key <= BsB || bits <= RADB) {
      int idx = atomicAdd(&lcount[1], 1);
      if (idx < LCAP) {
        ((unsigned char*)idxb[1])[j] = (unsigned char)(idx + 1);
        lst[1][idx] = make_int2(j, (int)bits);
      }
      if (key == BsB) { int cc = atomicAdd(&candn[1], 1); if (cc < CCAP) cand[1][cc] = bits; }
    }
  }
  __syncthreads();                                      // barrier 3
  const int nag = (lcount[rg] < LCAP) ? lcount[rg] : LCAP;

  // ---- phase 4: per-wave redundant rank of own row's boundary bin ----
  unsigned thrb;
  {
    int found = 0; unsigned fv = 0;
    const int Krem = KSEL - (rg ? cbB : cbA);
    const int ncg  = candn[rg];
    if (ncg <= CCAP) {                                  // normal: ncg tiny (~1-4)
      if (lane < ncg) {
        unsigned v = cand[rg][lane];
        int lt = 0, le = 0;
        for (int m = 0; m < ncg; ++m) { unsigned u = cand[rg][m]; lt += (u < v); le += (u <= v); }
        if (lt < Krem && le >= Krem) { found = 1; fv = v; }
      }
    } else {                                            // overflow (~never): rank whole list
      for (int e = lane; e < nag; e += 64) {
        unsigned v = (unsigned)lst[rg][e].y;
        int lt = 0, le = 0;
        for (int m = 0; m < nag; ++m) {
          unsigned u = (unsigned)lst[rg][m].y;
          lt += (u < v); le += (u <= v);
        }
        if (lt < KSEL && le >= KSEL) { found = 1; fv = v; }
      }
    }
    unsigned long long mk = __ballot(found != 0);
    unsigned d24 = (unsigned)__shfl((int)fv, __ffsll((long long)mk) - 1);
    thrb = d24 > RADB ? d24 : RADB;
  }

  // ---- phase 5: scores; thread (rg, tid&255) owns list entry ----
  const float* tdb = tdT ? tdT + (size_t)b * NN * CD : nullptr;
  const int e5 = tid & 255;
  if (e5 < nag) {
    int2 en = lst[rg][e5];
    int j = en.x;
    unsigned bits = (unsigned)en.y;
    float d2 = __uint_as_float(bits);
    const float4* sp4 = (const float4*)sdp4[rg];
    float a0 = 0.f, a1 = 0.f, a2 = 0.f, a3 = 0.f;
    if (tdb) {
      const float4* trow = (const float4*)(tdb + (size_t)j * CD);
#pragma unroll
      for (int q = 0; q < CD / 4; q += 4) {
        float4 x0 = sp4[q],     t0 = trow[q];
        float4 x1 = sp4[q + 1], t1 = trow[q + 1];
        float4 x2 = sp4[q + 2], t2 = trow[q + 2];
        float4 x3 = sp4[q + 3], t3 = trow[q + 3];
        a0 = fmaf(x0.x, t0.x, fmaf(x0.y, t0.y, fmaf(x0.z, t0.z, fmaf(x0.w, t0.w, a0))));
        a1 = fmaf(x1.x, t1.x, fmaf(x1.y, t1.y, fmaf(x1.z, t1.z, fmaf(x1.w, t1.w, a1))));
        a2 = fmaf(x2.x, t2.x, fmaf(x2.y, t2.y, fmaf(x2.z, t2.z, fmaf(x2.w, t2.w, a2))));
        a3 = fmaf(x3.x, t3.x, fmaf(x3.y, t3.y, fmaf(x3.z, t3.z, fmaf(x3.w, t3.w, a3))));
      }
    } else {
      const float* spx = (const float*)sdp4[rg];
      const float* tp  = td + (size_t)b * CD * NN + j;
#pragma unroll 8
      for (int c2 = 0; c2 < CD; ++c2) a0 = fmaf(spx[c2], tp[(size_t)c2 * NN], a0);
    }
    float sim = (a0 + a1) + (a2 + a3);
    float aj;
    if (addj) {
      aj = addj[(size_t)b * NN + j];
    } else {
      float l0 = tml[(size_t)b * 2 * NN + j];
      float l1 = tml[(size_t)b * 2 * NN + NN + j];
      float x  = l1 - l0;
      float sp = fmaxf(x, 0.0f) + log1pf(expf(-fabsf(x)));
      aj = fmaxf(-sp, -20.0f) - 0.1f * tu[(size_t)b * NN + j];
    }
    // boundary-bin tail beyond the 24th: not allowed -> p must be exactly 0
    float sco = (bits <= thrb) ? (sim - sqrtf(d2) + aj) : -1e30f;
    slist[rg][e5] = make_int2(j, __float_as_int(sco));
  }
  __syncthreads();                                      // barrier 4 (last)

  // ---- phase 6: per-wave redundant softmax + fused stats (own row) ----
  const float C1   = (1.0f / 0.07f) * 1.44269504089f;   // log2(e)/TEMP
  const float STEP = 2.0f / 15.0f;
  const float LN2  = 0.69314718056f;
  float m_ = -1e30f;
  for (int e = lane; e < nag; e += 64) m_ = fmaxf(m_, __int_as_float(slist[rg][e].y));
#pragma unroll
  for (int off = 32; off; off >>= 1) m_ = fmaxf(m_, __shfl_xor(m_, off));
  float zl = 0.f, eu = 0.f, e0 = 0.f, e1 = 0.f, e2 = 0.f;
  for (int e = lane; e < nag; e += 64) {
    int2 sv = slist[rg][e];
    float u  = (__int_as_float(sv.y) - m_) * C1;
    float ev = exp2f(u);
    int j = sv.x;
    float pz = -1.0f + STEP * (float)(j >> 8);
    float py = -1.0f + STEP * (float)((j >> 4) & 15);
    float px = -1.0f + STEP * (float)(j & 15);
    zl += ev; eu = fmaf(ev, u, eu);
    e0 = fmaf(ev, pz, e0); e1 = fmaf(ev, py, e1); e2 = fmaf(ev, px, e2);
  }
#pragma unroll
  for (int off = 32; off; off >>= 1) {
    zl += __shfl_xor(zl, off); eu += __shfl_xor(eu, off);
    e0 += __shfl_xor(e0, off); e1 += __shfl_xor(e1, off); e2 += __shfl_xor(e2, off);
  }
  const float invZ = 1.0f / zl;   // max(probs) == invZ exactly (top ev == 1)

  // ---- phase 7: expand + NT write; wave w covers 256 float4s of its row ----
  const int wl = w & 3;
  f4v* prow4 = (f4v*)(oprob + (size_t)(row0 + rg) * NN);
#pragma unroll
  for (int q = 0; q < 4; ++q) {
    int c = (q << 8) + (wl << 6) + lane;
    unsigned pk = idxb[rg][c];
    f4v v; v[0] = 0.f; v[1] = 0.f; v[2] = 0.f; v[3] = 0.f;
    if (pk) {
#pragma unroll
      for (int r = 0; r < 4; ++r) {
        unsigned u8 = (pk >> (8 * r)) & 0xFFu;
        if (u8) v[r] = exp2f((__int_as_float(slist[rg][u8 - 1].y) - m_) * C1) * invZ;
      }
    }
    __builtin_nontemporal_store(v, &prow4[c]);
  }

  // ---- epilogue: tid 0 (row 0) and tid 256 (row 1) hold their row's stats ----
  if ((tid & 255) == 0) {
    int i_ = i0 + rg, row = row0 + rg;
    float p0 = e0 * invZ, p1 = e1 * invZ, p2 = e2 * invZ;
    float ent = LN2 * (log2f(zl) - eu * invZ);
    float tz = -1.0f + STEP * (float)(i_ >> 8);
    float ty = -1.0f + STEP * (float)((i_ >> 4) & 15);
    float tx = -1.0f + STEP * (float)(i_ & 15);
    size_t r3 = (size_t)row * 3;
    oexp[r3 + 0] = p0; oexp[r3 + 1] = p1; oexp[r3 + 2] = p2;
    osrc[r3 + 0] = tz; osrc[r3 + 1] = ty; osrc[r3 + 2] = tx;
    size_t db = (size_t)b * 3 * NN;
    odisp[db + 0 * NN + i_] = p0 - tz;
    odisp[db + 1 * NN + i_] = p1 - ty;
    odisp[db + 2 * NN + i_] = p2 - tx;
    float ls0 = sml[(size_t)b * 2 * NN + i_];
    float ls1 = sml[(size_t)b * 2 * NN + NN + i_];
    float smv = 1.0f / (1.0f + expf(ls1 - ls0));
    oconf[(size_t)b * NN + i_] = invZ * smv;
    oent[(size_t)b * NN + i_]  = ent;
  }
}

extern "C" void kernel_launch(void* const* d_in, const int* in_sizes, int n_in,
                              void* d_out, int out_size, void* d_ws, size_t ws_size,
                              hipStream_t stream) {
  const float* sc  = (const float*)d_in[0];
  const float* tc  = (const float*)d_in[1];
  const float* sd  = (const float*)d_in[2];
  const float* td  = (const float*)d_in[3];
  const float* sml = (const float*)d_in[4];
  const float* tml = (const float*)d_in[5];
  const float* tu  = (const float*)d_in[7];
  // src_unc (d_in[6]) cancels in the row softmax -> unused

  float* out   = (float*)d_out;
  float* oexp  = out;
  float* odisp = oexp  + (size_t)BATCH * NN * 3;
  float* oprob = odisp + (size_t)BATCH * NN * 3;
  float* oconf = oprob + (size_t)BATCH * NN * NN;
  float* oent  = oconf + (size_t)BATCH * NN;
  float* osrc  = oent  + (size_t)BATCH * NN;

  size_t need = ((size_t)2 * BATCH * NN * CD + (size_t)BATCH * NN) * sizeof(float);
  float* tdT = nullptr; float* sdT = nullptr; float* adj = nullptr;
  if (ws_size >= need) {
    tdT = (float*)d_ws;
    sdT = tdT + (size_t)BATCH * NN * CD;
    adj = sdT + (size_t)BATCH * NN * CD;
    prep_all<<<256 + 32, 256, 0, stream>>>(td, sd, tml, tu, tdT, sdT, adj);
  }
  matcher_main<<<BATCH * NN / 2, 512, 0, stream>>>(sc, tc, sd, td, tdT, sdT, adj,
                                                   tml, tu, sml,
                                                   oexp, odisp, oprob, oconf, oent, osrc);
}